// Round 17
// baseline (73.130 us; speedup 1.0000x reference)
//
#include <hip/hip_runtime.h>
#include <stdint.h>

#define NPIX   16384
#define KC     8192
#define DD     64
#define EMS    8193          // embed row stride (K+1)
#define OUT_QUANT 0
#define OUT_DMIN  1048576
#define OUT_IND   (1048576 + 16384)

typedef _Float16 f16;
typedef _Float16 f16x8 __attribute__((ext_vector_type(8)));
typedef float    f32x4 __attribute__((ext_vector_type(4)));
typedef unsigned long long u64;

// async global->LDS, 16B/lane; dest = wave-uniform base (+lane*16 by HW)
__device__ __forceinline__ void gld_lds16(const void* g, void* l) {
    __builtin_amdgcn_global_load_lds(
        (const __attribute__((address_space(1))) uint32_t*)g,
        (__attribute__((address_space(3))) uint32_t*)l, 16, 0, 0);
}

// ---------------------------------------------------------------------------
// Fused prep, parallelized over (slot, element): 768 blocks.
// Blocks 0..511   : x -> f16 HI A3[8][NPIX][8]   (thread = one (s,n))
// Blocks 512..767 : embed -> f16 hi/lo B3[16][KC][8] (thread = one (s,k));
//                   the s==0 slice also computes masked +1024-biased norms.
// ---------------------------------------------------------------------------
__global__ __launch_bounds__(256)
void vq_prep(const float* __restrict__ x, const float* __restrict__ em,
             const int* __restrict__ cnt,
             f16* __restrict__ A3, f16* __restrict__ B3,
             float* __restrict__ cn) {
    const int b = blockIdx.x;
    if (b < 512) {
        int id = b * 256 + threadIdx.x;      // (s,n)
        int n = id & (NPIX - 1);
        int s = id >> 14;
        f16x8 hv;
#pragma unroll
        for (int j = 0; j < 8; ++j)
            hv[j] = (f16)x[(s * 8 + j) * NPIX + n];
        *(f16x8*)&A3[((u64)s * NPIX + n) * 8] = hv;
    } else {
        int id = (b - 512) * 256 + threadIdx.x;   // (s,k)
        int k = id & (KC - 1);
        int s = id >> 13;
        f16x8 hv, lv;
#pragma unroll
        for (int j = 0; j < 8; ++j) {
            float v = em[(s * 8 + j) * EMS + k];
            f16 h = (f16)v;
            hv[j] = h;
            lv[j] = (f16)(v - (float)h);
        }
        *(f16x8*)&B3[((u64)(s)     * KC + k) * 8] = hv;
        *(f16x8*)&B3[((u64)(s + 8) * KC + k) * 8] = lv;
        if (s == 0) {
            float s2 = 0.f;
#pragma unroll
            for (int d = 0; d < DD; ++d) {
                float v = em[d * EMS + k];
                s2 = fmaf(v, v, s2);
            }
            cn[k] = (cnt[k] < 1) ? 1.0e30f : (s2 + 1024.f);
        }
    }
}

// ---------------------------------------------------------------------------
// MFMA distance GEMM + fused per-block argmin, 2-phase pipelined.
// Product: Xh.E = Xh.Eh + Xh.El  -> 4 K-steps of 32 (K=128).
// Block: 128 pixels x 512 codes, 8 ns-subtiles of 64 codes. Wave w owns
// rows w*32..+31, all cols -> one pk group per block (16 total).
// A-fragments in regs from one-time global prologue. B double-buffered in
// LDS (2 x 16 KB = 32 KB). launch_bounds(256,4): 4 blocks/CU (128 KB LDS,
// 16 waves) -- grid 2048 = EXACTLY 2 generations of 1024 resident blocks,
// zero tail; 4 waves/SIMD hides the ds_read->MFMA and barrier latency.
// Epilogue: (f32,int) running min, 4 VALU/candidate.
// ---------------------------------------------------------------------------
__global__ __launch_bounds__(256, 4)
void vq_mfma(const f16* __restrict__ A3, const f16* __restrict__ B3,
             const float* __restrict__ cn, u64* __restrict__ pk) {
    __shared__ f16 Bs[2][8192];   // [buf][16 slot][64 code][8]

    const int bid = blockIdx.x;
    const int nb  = bid >> 7;        // 0..15 (512-code groups)
    const int mb  = bid & 127;       // 0..127 (128-pixel tiles)
    const int m0  = mb * 128;
    const int n0  = nb * 512;
    const int t = threadIdx.x, lane = t & 63, w = t >> 6;
    const int l15 = lane & 15, l4 = lane >> 4;
    const int wrow = m0 + w * 32;    // wave's 32 rows

    float bd[8];                     // [m 2][r 4] running min dist
    int   bc[8];                     // matching col
#pragma unroll
    for (int i = 0; i < 8; ++i) { bd[i] = 3.0e38f; bc[i] = 0x7fffffff; }

    const f32x4 zero4 = {0.f, 0.f, 0.f, 0.f};

    // ---- prologue: A fragments from global (held in regs all block) ----
    f16x8 afAll[2][2];               // [sa group][m]
#pragma unroll
    for (int s = 0; s < 2; ++s)
#pragma unroll
        for (int m = 0; m < 2; ++m)
            afAll[s][m] = *(const f16x8*)
                &A3[((u64)(s * 4 + l4) * NPIX + wrow + m * 16 + l15) * 8];

    // ---- stage B(ns=0) into buf 0: 16 x 1KB instrs, 4 per wave ----
#pragma unroll
    for (int j = 0; j < 4; ++j) {
        int q = w * 4 + j;           // slot 0..15
        gld_lds16(B3 + ((u64)q * KC + n0 + lane) * 8, &Bs[0][q * 512]);
    }
    __syncthreads();                 // B(0) resident

    static const int sidx_t[4] = {0, 1, 0, 1};
    static const int sb_t[4]   = {0, 4, 8, 12};

#pragma unroll 1
    for (int ns = 0; ns < 8; ++ns) {
        const int nsub = n0 + ns * 64;
        const f16* bl = &Bs[ns & 1][0];

        // ---- issue next-ns B staging into the idle buffer ----
        if (ns < 7) {
            f16* bo = &Bs[(ns & 1) ^ 1][0];
#pragma unroll
            for (int j = 0; j < 4; ++j) {
                int q = w * 4 + j;
                gld_lds16(B3 + ((u64)q * KC + nsub + 64 + lane) * 8,
                          bo + q * 512);
            }
        }

        f32x4 acc[2][4];
#pragma unroll
        for (int m = 0; m < 2; ++m)
#pragma unroll
            for (int n = 0; n < 4; ++n) acc[m][n] = zero4;

#pragma unroll
        for (int kt = 0; kt < 4; ++kt) {
            const int sb = sb_t[kt], si = sidx_t[kt];
            f16x8 bf[4];
#pragma unroll
            for (int n = 0; n < 4; ++n)
                bf[n] = *(const f16x8*)
                    &bl[((sb + l4) * 64 + n * 16 + l15) * 8];
#pragma unroll
            for (int m = 0; m < 2; ++m)
#pragma unroll
                for (int n = 0; n < 4; ++n)
                    acc[m][n] = __builtin_amdgcn_mfma_f32_16x16x32_f16(
                        afAll[si][m], bf[n], acc[m][n], 0, 0, 0);
        }

        // ---- epilogue: dist = cn(biased) - 2*dot; (f32,int) running min ----
        const int cb = nsub + l15;
        float cnv[4];
        int   col[4];
#pragma unroll
        for (int n = 0; n < 4; ++n) { col[n] = cb + n * 16; cnv[n] = cn[col[n]]; }
#pragma unroll
        for (int m = 0; m < 2; ++m)
#pragma unroll
            for (int r = 0; r < 4; ++r) {
                const int i = m * 4 + r;
#pragma unroll
                for (int n = 0; n < 4; ++n) {     // ascending col: strict <
                    float dist = fmaf(-2.f, acc[m][n][r], cnv[n]);
                    if (dist < bd[i]) { bd[i] = dist; bc[i] = col[n]; }
                }
            }

        if (ns < 7) __syncthreads();   // staged B(ns+1) resident; bufs swap
    }

    // ---- 16-lane (l15) reduce with col tie-break; pack once; write ----
    const u64 pkb = (u64)nb * NPIX;
#pragma unroll
    for (int m = 0; m < 2; ++m)
#pragma unroll
        for (int r = 0; r < 4; ++r) {
            float d = bd[m * 4 + r];
            int   c = bc[m * 4 + r];
#pragma unroll
            for (int off = 1; off < 16; off <<= 1) {
                float od = __shfl_xor(d, off, 64);
                int   oc = __shfl_xor(c, off, 64);
                if (od < d || (od == d && oc < c)) { d = od; c = oc; }
            }
            if (l15 == 0) {
                int row = wrow + m * 16 + l4 * 4 + r;
                pk[pkb + row] = ((u64)__float_as_uint(d) << 32) | (u64)c;
            }
        }
}

// ---------------------------------------------------------------------------
// Pick: 64-thread blocks (256 blocks -> full-chip TLP for the latency-bound
// gathers). Global top-2 from 16 group minima, exact fp32 recompute, strict
// argmin semantics, write dmin + ind + winning index for the gather.
// ---------------------------------------------------------------------------
__global__ __launch_bounds__(64)
void vq_pick(const float* __restrict__ x, const float* __restrict__ em,
             const float* __restrict__ cn, const u64* __restrict__ pk,
             float* __restrict__ out, int* __restrict__ ib) {
    int n = blockIdx.x * 64 + threadIdx.x;
    u64 b1 = ~0ull, b2 = ~0ull;
#pragma unroll 4
    for (int g = 0; g < 16; ++g) {
        u64 v = pk[(u64)g * NPIX + n];
        if (v < b1)      { b2 = b1; b1 = v; }
        else if (v < b2) { b2 = v; }
    }
    int i1 = (int)(b1 & 0xffffffffull);
    int i2 = (int)(b2 & 0xffffffffull);

    float rn = 0.f, dot1 = 0.f, dot2 = 0.f;
#pragma unroll 8
    for (int d = 0; d < DD; ++d) {
        float xv = x[d * NPIX + n];
        rn   = fmaf(xv, xv, rn);
        dot1 = fmaf(xv, em[d * EMS + i1], dot1);
        dot2 = fmaf(xv, em[d * EMS + i2], dot2);
    }
    float D1 = rn + (cn[i1] - 1024.f) - 2.f * dot1;
    float D2 = rn + (cn[i2] - 1024.f) - 2.f * dot2;
    int bi; float db;
    if (D2 < D1 || (D2 == D1 && i2 < i1)) { bi = i2; db = D2; }
    else                                  { bi = i1; db = D1; }

    out[OUT_DMIN + n] = db;
    out[OUT_IND  + n] = (float)bi;
    ib[n] = bi;
}

// ---------------------------------------------------------------------------
// Gather: quant output. 4096 blocks -> huge TLP for scattered em reads;
// writes fully coalesced.
// ---------------------------------------------------------------------------
__global__ __launch_bounds__(256)
void vq_gather(const float* __restrict__ em, const int* __restrict__ ib,
               float* __restrict__ out) {
    int id = blockIdx.x * 256 + threadIdx.x;
    int n = id & (NPIX - 1);
    int d = id >> 14;
    out[OUT_QUANT + (u64)d * NPIX + n] = em[(u64)d * EMS + ib[n]];
}

// ---------------------------------------------------------------------------
extern "C" void kernel_launch(void* const* d_in, const int* in_sizes, int n_in,
                              void* d_out, int out_size, void* d_ws, size_t ws_size,
                              hipStream_t stream) {
    const float* x     = (const float*)d_in[0];   // [1,64,128,128]
    const float* embed = (const float*)d_in[1];   // [64,8193]
    const int*   cnt   = (const int*)d_in[2];     // [8192]
    float* out = (float*)d_out;

    // ws layout: A3 2MB | B3 2MB | pk 2MB | cn 32KB | ib 64KB  (6.1 MB)
    f16*   A3 = (f16*)d_ws;
    f16*   B3 = (f16*)((char*)d_ws + (size_t)2 * 1024 * 1024);
    u64*   pk = (u64*)((char*)d_ws + (size_t)4 * 1024 * 1024);
    float* cn = (float*)((char*)d_ws + (size_t)6 * 1024 * 1024);
    int*   ib = (int*)((char*)d_ws + (size_t)6 * 1024 * 1024 + 65536);

    vq_prep<<<768, 256, 0, stream>>>(x, embed, cnt, A3, B3, cn);
    vq_mfma<<<128 * 16, 256, 0, stream>>>(A3, B3, cn, pk);
    vq_pick<<<NPIX / 64, 64, 0, stream>>>(x, embed, cn, pk, out, ib);
    vq_gather<<<NPIX * DD / 256, 256, 0, stream>>>(embed, ib, out);
}

// Round 18
// 70.821 us; speedup vs baseline: 1.0326x; 1.0326x over previous
//
#include <hip/hip_runtime.h>
#include <stdint.h>

#define NPIX   16384
#define KC     8192
#define DD     64
#define EMS    8193          // embed row stride (K+1)
#define OUT_QUANT 0
#define OUT_DMIN  1048576
#define OUT_IND   (1048576 + 16384)

typedef _Float16 f16;
typedef _Float16 f16x8 __attribute__((ext_vector_type(8)));
typedef float    f32x4 __attribute__((ext_vector_type(4)));
typedef unsigned long long u64;

// async global->LDS, 16B/lane; dest = wave-uniform base (+lane*16 by HW)
__device__ __forceinline__ void gld_lds16(const void* g, void* l) {
    __builtin_amdgcn_global_load_lds(
        (const __attribute__((address_space(1))) uint32_t*)g,
        (__attribute__((address_space(3))) uint32_t*)l, 16, 0, 0);
}

// ---------------------------------------------------------------------------
// Fused prep, parallelized over (slot, element): 768 blocks.
// Blocks 0..511   : x -> f16 HI A3[8][NPIX][8]   (thread = one (s,n))
// Blocks 512..767 : embed -> f16 hi/lo B3[16][KC][8] (thread = one (s,k));
//                   the s==0 slice also computes masked +1024-biased norms.
// ---------------------------------------------------------------------------
__global__ __launch_bounds__(256)
void vq_prep(const float* __restrict__ x, const float* __restrict__ em,
             const int* __restrict__ cnt,
             f16* __restrict__ A3, f16* __restrict__ B3,
             float* __restrict__ cn) {
    const int b = blockIdx.x;
    if (b < 512) {
        int id = b * 256 + threadIdx.x;      // (s,n)
        int n = id & (NPIX - 1);
        int s = id >> 14;
        f16x8 hv;
#pragma unroll
        for (int j = 0; j < 8; ++j)
            hv[j] = (f16)x[(s * 8 + j) * NPIX + n];
        *(f16x8*)&A3[((u64)s * NPIX + n) * 8] = hv;
    } else {
        int id = (b - 512) * 256 + threadIdx.x;   // (s,k)
        int k = id & (KC - 1);
        int s = id >> 13;
        f16x8 hv, lv;
#pragma unroll
        for (int j = 0; j < 8; ++j) {
            float v = em[(s * 8 + j) * EMS + k];
            f16 h = (f16)v;
            hv[j] = h;
            lv[j] = (f16)(v - (float)h);
        }
        *(f16x8*)&B3[((u64)(s)     * KC + k) * 8] = hv;
        *(f16x8*)&B3[((u64)(s + 8) * KC + k) * 8] = lv;
        if (s == 0) {
            float s2 = 0.f;
#pragma unroll
            for (int d = 0; d < DD; ++d) {
                float v = em[d * EMS + k];
                s2 = fmaf(v, v, s2);
            }
            cn[k] = (cnt[k] < 1) ? 1.0e30f : (s2 + 1024.f);
        }
    }
}

// ---------------------------------------------------------------------------
// MFMA distance GEMM + fused per-block argmin, 2-phase pipelined.
// Product: Xh.E = Xh.Eh + Xh.El  -> 4 K-steps of 32 (K=128).
// Block: 128 pixels x 512 codes, 8 ns-subtiles of 64 codes. Wave w owns
// rows w*32..+31, all cols -> one pk group per block (16 total).
// A-fragments in regs from one-time global prologue. B double-buffered in
// LDS (2 x 16 KB). Epilogue uses slot-in-mantissa packed min: 3 VALU per
// candidate (fma dist, and_or pack slot into low-5 mantissa bits, min) --
// bd/bc pair and cndmasks eliminated; mantissa corruption <=0.008 is
// covered by the exact top-2 recompute; slot order == col order preserves
// the ascending-col strict-< tie-break.
// ---------------------------------------------------------------------------
__global__ __launch_bounds__(256, 4)
void vq_mfma(const f16* __restrict__ A3, const f16* __restrict__ B3,
             const float* __restrict__ cn, u64* __restrict__ pk) {
    __shared__ f16 Bs[2][8192];   // [buf][16 slot][64 code][8]

    const int bid = blockIdx.x;
    const int nb  = bid >> 7;        // 0..15 (512-code groups)
    const int mb  = bid & 127;       // 0..127 (128-pixel tiles)
    const int m0  = mb * 128;
    const int n0  = nb * 512;
    const int t = threadIdx.x, lane = t & 63, w = t >> 6;
    const int l15 = lane & 15, l4 = lane >> 4;
    const int wrow = m0 + w * 32;    // wave's 32 rows

    float bm[8];                     // [m 2][r 4] packed (dist|slot) min
#pragma unroll
    for (int i = 0; i < 8; ++i) bm[i] = 3.0e38f;

    const f32x4 zero4 = {0.f, 0.f, 0.f, 0.f};

    // ---- prologue: A fragments from global (held in regs all block) ----
    f16x8 afAll[2][2];               // [sa group][m]
#pragma unroll
    for (int s = 0; s < 2; ++s)
#pragma unroll
        for (int m = 0; m < 2; ++m)
            afAll[s][m] = *(const f16x8*)
                &A3[((u64)(s * 4 + l4) * NPIX + wrow + m * 16 + l15) * 8];

    // ---- stage B(ns=0) into buf 0: 16 x 1KB instrs, 4 per wave ----
#pragma unroll
    for (int j = 0; j < 4; ++j) {
        int q = w * 4 + j;           // slot 0..15
        gld_lds16(B3 + ((u64)q * KC + n0 + lane) * 8, &Bs[0][q * 512]);
    }
    __syncthreads();                 // B(0) resident

    static const int sidx_t[4] = {0, 1, 0, 1};
    static const int sb_t[4]   = {0, 4, 8, 12};

#pragma unroll 1
    for (int ns = 0; ns < 8; ++ns) {
        const int nsub = n0 + ns * 64;
        const f16* bl = &Bs[ns & 1][0];

        // ---- issue next-ns B staging into the idle buffer ----
        if (ns < 7) {
            f16* bo = &Bs[(ns & 1) ^ 1][0];
#pragma unroll
            for (int j = 0; j < 4; ++j) {
                int q = w * 4 + j;
                gld_lds16(B3 + ((u64)q * KC + nsub + 64 + lane) * 8,
                          bo + q * 512);
            }
        }

        f32x4 acc[2][4];
#pragma unroll
        for (int m = 0; m < 2; ++m)
#pragma unroll
            for (int n = 0; n < 4; ++n) acc[m][n] = zero4;

#pragma unroll
        for (int kt = 0; kt < 4; ++kt) {
            const int sb = sb_t[kt], si = sidx_t[kt];
            f16x8 bf[4];
#pragma unroll
            for (int n = 0; n < 4; ++n)
                bf[n] = *(const f16x8*)
                    &bl[((sb + l4) * 64 + n * 16 + l15) * 8];
#pragma unroll
            for (int m = 0; m < 2; ++m)
#pragma unroll
                for (int n = 0; n < 4; ++n)
                    acc[m][n] = __builtin_amdgcn_mfma_f32_16x16x32_f16(
                        afAll[si][m], bf[n], acc[m][n], 0, 0, 0);
        }

        // ---- epilogue: dist = cn(biased) - 2*dot; packed running min ----
        const int cb = nsub + l15;
        float cnv[4];
#pragma unroll
        for (int n = 0; n < 4; ++n) cnv[n] = cn[cb + n * 16];
#pragma unroll
        for (int m = 0; m < 2; ++m)
#pragma unroll
            for (int r = 0; r < 4; ++r) {
                const int i = m * 4 + r;
                float b = bm[i];
#pragma unroll
                for (int n = 0; n < 4; ++n) {
                    float dist = fmaf(-2.f, acc[m][n][r], cnv[n]);
                    uint32_t pd = (__float_as_uint(dist) & 0xFFFFFFE0u)
                                | (uint32_t)(ns * 4 + n);
                    b = fminf(b, __uint_as_float(pd));
                }
                bm[i] = b;
            }

        if (ns < 7) __syncthreads();   // staged B(ns+1) resident; bufs swap
    }

    // ---- unpack slot -> col; 16-lane reduce; write pk ----
    const u64 pkb = (u64)nb * NPIX;
#pragma unroll
    for (int m = 0; m < 2; ++m)
#pragma unroll
        for (int r = 0; r < 4; ++r) {
            float d = bm[m * 4 + r];
            uint32_t slot = __float_as_uint(d) & 31u;
            int c = n0 + (int)(slot >> 2) * 64 + (int)(slot & 3) * 16 + l15;
#pragma unroll
            for (int off = 1; off < 16; off <<= 1) {
                float od = __shfl_xor(d, off, 64);
                int   oc = __shfl_xor(c, off, 64);
                if (od < d || (od == d && oc < c)) { d = od; c = oc; }
            }
            if (l15 == 0) {
                int row = wrow + m * 16 + l4 * 4 + r;
                pk[pkb + row] = ((u64)__float_as_uint(d) << 32) | (u64)c;
            }
        }
}

// ---------------------------------------------------------------------------
// Fused pick + gather. 256 blocks x 256 threads. Wave 0 picks 64 rows
// (top-2 from 16 group minima, exact fp32 recompute, strict argmin
// semantics, writes dmin + ind), hands indices via LDS; then all 4 waves
// write the 64x64 quant stripe with coalesced stores.
// ---------------------------------------------------------------------------
__global__ __launch_bounds__(256)
void vq_pick_gather(const float* __restrict__ x, const float* __restrict__ em,
                    const float* __restrict__ cn, const u64* __restrict__ pk,
                    float* __restrict__ out) {
    __shared__ int ibs[64];
    const int tid = threadIdx.x;
    const int nb  = blockIdx.x;

    if (tid < 64) {
        int n = nb * 64 + tid;
        u64 b1 = ~0ull, b2 = ~0ull;
#pragma unroll 4
        for (int g = 0; g < 16; ++g) {
            u64 v = pk[(u64)g * NPIX + n];
            if (v < b1)      { b2 = b1; b1 = v; }
            else if (v < b2) { b2 = v; }
        }
        int i1 = (int)(b1 & 0xffffffffull);
        int i2 = (int)(b2 & 0xffffffffull);

        float rn = 0.f, dot1 = 0.f, dot2 = 0.f;
#pragma unroll 8
        for (int d = 0; d < DD; ++d) {
            float xv = x[d * NPIX + n];
            rn   = fmaf(xv, xv, rn);
            dot1 = fmaf(xv, em[d * EMS + i1], dot1);
            dot2 = fmaf(xv, em[d * EMS + i2], dot2);
        }
        float D1 = rn + (cn[i1] - 1024.f) - 2.f * dot1;
        float D2 = rn + (cn[i2] - 1024.f) - 2.f * dot2;
        int bi; float db;
        if (D2 < D1 || (D2 == D1 && i2 < i1)) { bi = i2; db = D2; }
        else                                  { bi = i1; db = D1; }

        out[OUT_DMIN + n] = db;
        out[OUT_IND  + n] = (float)bi;
        ibs[tid] = bi;
    }
    __syncthreads();

    const int nn = tid & 63;          // n within block
    const int d0 = (tid >> 6) * 16;   // 4 waves x 16 d rows
    const int n  = nb * 64 + nn;
    const int bi = ibs[nn];
#pragma unroll
    for (int j = 0; j < 16; ++j) {
        int d = d0 + j;
        out[OUT_QUANT + (u64)d * NPIX + n] = em[(u64)d * EMS + bi];
    }
}

// ---------------------------------------------------------------------------
extern "C" void kernel_launch(void* const* d_in, const int* in_sizes, int n_in,
                              void* d_out, int out_size, void* d_ws, size_t ws_size,
                              hipStream_t stream) {
    const float* x     = (const float*)d_in[0];   // [1,64,128,128]
    const float* embed = (const float*)d_in[1];   // [64,8193]
    const int*   cnt   = (const int*)d_in[2];     // [8192]
    float* out = (float*)d_out;

    // ws layout: A3 2MB | B3 2MB | pk 2MB | cn 32KB  (6.03 MB)
    f16*   A3 = (f16*)d_ws;
    f16*   B3 = (f16*)((char*)d_ws + (size_t)2 * 1024 * 1024);
    u64*   pk = (u64*)((char*)d_ws + (size_t)4 * 1024 * 1024);
    float* cn = (float*)((char*)d_ws + (size_t)6 * 1024 * 1024);

    vq_prep<<<768, 256, 0, stream>>>(x, embed, cnt, A3, B3, cn);
    vq_mfma<<<128 * 16, 256, 0, stream>>>(A3, B3, cn, pk);
    vq_pick_gather<<<NPIX / 64, 256, 0, stream>>>(x, embed, cn, pk, out);
}